// Round 1
// baseline (3193.167 us; speedup 1.0000x reference)
//
#include <hip/hip_runtime.h>

#define T_TOK 32768
#define EDIM  1024
#define HDIM  4096
#define NEXP  8
#define BM    128
#define BH    128
#define BK    16
#define NHT   (HDIM / BH)   // 32 H-tiles

// ---------------------------------------------------------------------------
// Kernel A: fused  score_partial = relu(x @ W1 + b1) @ W2   for one H-tile.
// Grid: (NHT, T_TOK/BM). Block: 256 threads (16x16), each owns an 8x8 tile.
// partial_mode=1: write per-H-tile partial scores to dst[htile][T][8] (determ.)
// partial_mode=0: atomicAdd into dst[T][8] (fallback if ws too small).
// ---------------------------------------------------------------------------
__global__ __launch_bounds__(256) void score_gemm_kernel(
    const float* __restrict__ x, const float* __restrict__ w1,
    const float* __restrict__ b1, const float* __restrict__ w2,
    float* __restrict__ dst, int partial_mode)
{
    __shared__ float xs[BK][BM + 4];     // +4 pad: conflict-free, 16B-aligned rows
    __shared__ float wsh[BK][BH];
    __shared__ float w2s[BH * NEXP];     // 4 KB W2 tile
    __shared__ float b1s[BH];

    const int htile = blockIdx.x;
    const int mtile = blockIdx.y;
    const int h0 = htile * BH;
    const int m0 = mtile * BM;
    const int tid = threadIdx.x;
    const int tx = tid & 15;
    const int ty = tid >> 4;

    // one-time staging of W2 tile + b1 tile
    {
        float4 v = *reinterpret_cast<const float4*>(&w2[(size_t)h0 * NEXP + tid * 4]);
        *reinterpret_cast<float4*>(&w2s[tid * 4]) = v;
        if (tid < BH) b1s[tid] = b1[h0 + tid];
    }

    float acc[8][8];
#pragma unroll
    for (int i = 0; i < 8; ++i)
#pragma unroll
        for (int j = 0; j < 8; ++j) acc[i][j] = 0.f;

    const int e_off = tid & 15;   // k within tile (x loader)
    const int t_row = tid >> 4;   // token group (x loader)
    const int h_off = tid & 127;  // h within tile (w1 loader)
    const int k_off = tid >> 7;   // k group (w1 loader)

    for (int k0 = 0; k0 < EDIM; k0 += BK) {
        __syncthreads();
#pragma unroll
        for (int r = 0; r < 8; ++r) {
            int tok = t_row + r * 16;
            xs[e_off][tok] = x[(size_t)(m0 + tok) * EDIM + k0 + e_off];
        }
#pragma unroll
        for (int r = 0; r < 8; ++r) {
            int k = k_off + r * 2;
            wsh[k][h_off] = w1[(size_t)(k0 + k) * HDIM + h0 + h_off];
        }
        __syncthreads();
#pragma unroll
        for (int k = 0; k < BK; ++k) {
            float a[8], b[8];
            *reinterpret_cast<float4*>(&a[0]) = *reinterpret_cast<const float4*>(&xs[k][ty * 8]);
            *reinterpret_cast<float4*>(&a[4]) = *reinterpret_cast<const float4*>(&xs[k][ty * 8 + 4]);
            *reinterpret_cast<float4*>(&b[0]) = *reinterpret_cast<const float4*>(&wsh[k][tx * 8]);
            *reinterpret_cast<float4*>(&b[4]) = *reinterpret_cast<const float4*>(&wsh[k][tx * 8 + 4]);
#pragma unroll
            for (int i = 0; i < 8; ++i)
#pragma unroll
                for (int j = 0; j < 8; ++j)
                    acc[i][j] = fmaf(a[i], b[j], acc[i][j]);
        }
    }

    // epilogue: bias + relu + fold W2 (8 h-cols) into 8 expert partials / token
    float sred[8][NEXP];
#pragma unroll
    for (int i = 0; i < 8; ++i) {
        float hv[8];
#pragma unroll
        for (int j = 0; j < 8; ++j)
            hv[j] = fmaxf(acc[i][j] + b1s[tx * 8 + j], 0.f);
#pragma unroll
        for (int n = 0; n < NEXP; ++n) {
            float s = 0.f;
#pragma unroll
            for (int j = 0; j < 8; ++j)
                s = fmaf(hv[j], w2s[(tx * 8 + j) * NEXP + n], s);
            sred[i][n] = s;
        }
    }
    // reduce across the 16 tx-threads (lane bits 0..3) — fixed order, determ.
#pragma unroll
    for (int i = 0; i < 8; ++i)
#pragma unroll
        for (int n = 0; n < NEXP; ++n) {
            float v = sred[i][n];
            v += __shfl_xor(v, 1);
            v += __shfl_xor(v, 2);
            v += __shfl_xor(v, 4);
            v += __shfl_xor(v, 8);
            sred[i][n] = v;
        }

    if (tx == 0) {
        if (partial_mode) {
            float* slice = dst + (size_t)htile * T_TOK * NEXP;
#pragma unroll
            for (int i = 0; i < 8; ++i)
#pragma unroll
                for (int n = 0; n < NEXP; ++n)
                    slice[(size_t)(m0 + ty * 8 + i) * NEXP + n] = sred[i][n];
        } else {
#pragma unroll
            for (int i = 0; i < 8; ++i)
#pragma unroll
                for (int n = 0; n < NEXP; ++n)
                    atomicAdd(&dst[(size_t)(m0 + ty * 8 + i) * NEXP + n], sred[i][n]);
        }
    }
}

// ---------------------------------------------------------------------------
// Kernel B: sum partials (fixed order) + b2, top-2 (lowest-index tie-break,
// matching jax.lax.top_k), masked softmax, write router weights + indices.
// ---------------------------------------------------------------------------
__global__ __launch_bounds__(256) void router_finish_kernel(
    const float* __restrict__ part, const float* __restrict__ b2,
    float* __restrict__ out, int nparts, int partial_mode)
{
    int t = blockIdx.x * 256 + threadIdx.x;
    if (t >= T_TOK) return;

    float s[NEXP];
    if (partial_mode) {
#pragma unroll
        for (int n = 0; n < NEXP; ++n) s[n] = 0.f;
        for (int p = 0; p < nparts; ++p) {
            const float* ps = part + (size_t)p * T_TOK * NEXP + (size_t)t * NEXP;
            float4 v0 = *reinterpret_cast<const float4*>(ps);
            float4 v1 = *reinterpret_cast<const float4*>(ps + 4);
            s[0] += v0.x; s[1] += v0.y; s[2] += v0.z; s[3] += v0.w;
            s[4] += v1.x; s[5] += v1.y; s[6] += v1.z; s[7] += v1.w;
        }
    } else {
        const float* ps = out + (size_t)t * NEXP;
        float4 v0 = *reinterpret_cast<const float4*>(ps);
        float4 v1 = *reinterpret_cast<const float4*>(ps + 4);
        s[0] = v0.x; s[1] = v0.y; s[2] = v0.z; s[3] = v0.w;
        s[4] = v1.x; s[5] = v1.y; s[6] = v1.z; s[7] = v1.w;
    }
#pragma unroll
    for (int n = 0; n < NEXP; ++n) s[n] += b2[n];

    int i1 = 0; float v1 = s[0];
#pragma unroll
    for (int n = 1; n < NEXP; ++n) { if (s[n] > v1) { v1 = s[n]; i1 = n; } }
    int i2 = -1; float v2 = -3.402823466e38f;
#pragma unroll
    for (int n = 0; n < NEXP; ++n) { if (n != i1 && s[n] > v2) { v2 = s[n]; i2 = n; } }

    float e2 = expf(v2 - v1);           // softmax over the two kept logits
    float denom = 1.f + e2;
    float p1 = 1.f / denom;
    float p2 = e2 / denom;

#pragma unroll
    for (int n = 0; n < NEXP; ++n)
        out[(size_t)t * NEXP + n] = (n == i1) ? p1 : ((n == i2) ? p2 : 0.f);
    // topk_idx appended after router_output, written as float values
    out[(size_t)T_TOK * NEXP + (size_t)t * 2 + 0] = (float)i1;
    out[(size_t)T_TOK * NEXP + (size_t)t * 2 + 1] = (float)i2;
}

extern "C" void kernel_launch(void* const* d_in, const int* in_sizes, int n_in,
                              void* d_out, int out_size, void* d_ws, size_t ws_size,
                              hipStream_t stream)
{
    const float* x  = (const float*)d_in[0];
    const float* w1 = (const float*)d_in[1];
    const float* b1 = (const float*)d_in[2];
    const float* w2 = (const float*)d_in[3];
    const float* b2 = (const float*)d_in[4];
    float* out = (float*)d_out;

    const size_t need = (size_t)NHT * T_TOK * NEXP * sizeof(float);  // 32 MB
    dim3 grid(NHT, T_TOK / BM);  // (32, 256)

    if (ws_size >= need) {
        float* part = (float*)d_ws;
        score_gemm_kernel<<<grid, 256, 0, stream>>>(x, w1, b1, w2, part, 1);
        router_finish_kernel<<<T_TOK / 256, 256, 0, stream>>>(part, b2, out, NHT, 1);
    } else {
        hipMemsetAsync(out, 0, (size_t)T_TOK * NEXP * sizeof(float), stream);
        score_gemm_kernel<<<grid, 256, 0, stream>>>(x, w1, b1, w2, out, 0);
        router_finish_kernel<<<T_TOK / 256, 256, 0, stream>>>(nullptr, b2, out, 0, 0);
    }
}

// Round 4
// 1024.731 us; speedup vs baseline: 3.1161x; 3.1161x over previous
//
#include <hip/hip_runtime.h>

#define T_TOK 32768
#define EDIM  1024
#define HDIM  4096
#define NEXP  8
#define TAU   2.5e-4f

// ===========================================================================
// fp16 split-precision MFMA path (3 passes):
//   x = xh + 2^-11*xl', w1 = wh + 2^-11*wl'  (fp16 RN, lo pre-scaled by 2^11)
//   accA += xh*wh ; accM += xh*wl' + xl'*wh ; score_h = accA + accM*2^-11
//   per-element error ~2^-22|x| -> score error ~ fp32-ordering noise level.
// Near-tie tokens (gap < TAU) get an exact fp32 recompute (deterministic).
// ===========================================================================

typedef _Float16 f16x8 __attribute__((ext_vector_type(8)));
typedef _Float16 f16x4 __attribute__((ext_vector_type(4)));
typedef __attribute__((ext_vector_type(4))) float f32x4;
#define MFMA16(a, b, c) __builtin_amdgcn_mfma_f32_16x16x32_f16(a, b, c, 0, 0, 0)

__device__ __forceinline__ void gload16(const void* g, void* l) {
    __builtin_amdgcn_global_load_lds(
        (const __attribute__((address_space(1))) void*)g,
        (__attribute__((address_space(3))) void*)l, 16, 0, 0);
}

struct HL { _Float16 hi, lo; };

// RN split: x ~= hi + lo * 2^-11, |err| <= 2^-22 |x|
__device__ __forceinline__ HL splitf16(float x) {
    HL r;
    _Float16 h = (_Float16)x;
    float res = x - (float)h;          // exact in fp32
    r.hi = h;
    r.lo = (_Float16)(res * 2048.0f);
    return r;
}

__global__ __launch_bounds__(256) void split_x_kernel(
    const float* __restrict__ x, _Float16* __restrict__ hi,
    _Float16* __restrict__ lo, int n4)
{
    int i = blockIdx.x * 256 + threadIdx.x;
    int stride = gridDim.x * 256;
    for (; i < n4; i += stride) {
        float4 v = ((const float4*)x)[i];
        HL a = splitf16(v.x), b = splitf16(v.y), c = splitf16(v.z), d = splitf16(v.w);
        f16x4 h, l;
        h[0] = a.hi; h[1] = b.hi; h[2] = c.hi; h[3] = d.hi;
        l[0] = a.lo; l[1] = b.lo; l[2] = c.lo; l[3] = d.lo;
        *(f16x4*)&hi[i * 4] = h;
        *(f16x4*)&lo[i * 4] = l;
    }
}

// w1 [1024][4096] f32  ->  w1t_hi/lo [4096][1024] fp16 (transposed + split)
__global__ __launch_bounds__(256) void split_w1t_kernel(
    const float* __restrict__ w1, _Float16* __restrict__ thi,
    _Float16* __restrict__ tlo)
{
    __shared__ float t[64][65];
    const int ht = blockIdx.x;   // 64 h-tiles
    const int et = blockIdx.y;   // 16 e-tiles
    const int tid = threadIdx.x;
    const int er = tid >> 6, hc = tid & 63;
#pragma unroll
    for (int rr = 0; rr < 16; ++rr) {
        int e = rr * 4 + er;
        t[e][hc] = w1[(size_t)(et * 64 + e) * HDIM + ht * 64 + hc];
    }
    __syncthreads();
    const int hl = tid >> 2, eg = tid & 3;
    HL v[16];
#pragma unroll
    for (int j = 0; j < 16; ++j) v[j] = splitf16(t[eg * 16 + j][hl]);
    size_t base = (size_t)(ht * 64 + hl) * EDIM + et * 64 + eg * 16;
#pragma unroll
    for (int q = 0; q < 4; ++q) {
        f16x4 a, b;
#pragma unroll
        for (int z = 0; z < 4; ++z) { a[z] = v[q * 4 + z].hi; b[z] = v[q * 4 + z].lo; }
        *(f16x4*)&thi[base + q * 4] = a;
        *(f16x4*)&tlo[base + q * 4] = b;
    }
}

// Fused MFMA GEMM + relu/bias + W2 fold. Grid (32 htiles, 256 mtiles), 256 thr.
// LDS tiles [128 rows][32 k] fp16, 64B rows; XOR swizzle on 16B slots:
// LDS slot t of row r holds global slot t ^ ((r>>1)&3)  (both-sides, rule #21).
__global__ __launch_bounds__(256, 2) void mfma_score_kernel(
    const _Float16* __restrict__ xhi, const _Float16* __restrict__ xlo,
    const _Float16* __restrict__ whi, const _Float16* __restrict__ wlo,
    const float* __restrict__ b1, const float* __restrict__ w2,
    float* __restrict__ part)
{
    __shared__ __align__(16) _Float16 Ahi[128 * 32], Alo[128 * 32];
    __shared__ __align__(16) _Float16 Bhi[128 * 32], Blo[128 * 32];

    const int ht = blockIdx.x;
    const int m0 = blockIdx.y * 128;
    const int h0 = ht * 128;
    const int tid = threadIdx.x;
    const int l = tid & 63;
    const int wid = tid >> 6;
    const int wm = wid >> 1, wn = wid & 1;

    const int srow = tid >> 2;
    const int sg = (tid & 3) ^ ((srow >> 1) & 3);
    const size_t xa0 = (size_t)(m0 + srow) * EDIM + sg * 8;
    const size_t xa1 = (size_t)(m0 + 64 + srow) * EDIM + sg * 8;
    const size_t wa0 = (size_t)(h0 + srow) * EDIM + sg * 8;
    const size_t wa1 = (size_t)(h0 + 64 + srow) * EDIM + sg * 8;
    const int ldst = tid * 16;

    const int lrow = l & 15, lslot = l >> 4;
    const int rslot = lslot ^ ((lrow >> 1) & 3);
    const int aoff = (wm * 64 + lrow) * 64 + rslot * 16;
    const int boff = (wn * 64 + lrow) * 64 + rslot * 16;

    f32x4 accA[4][4], accM[4][4];
    const f32x4 zz = {0.f, 0.f, 0.f, 0.f};
#pragma unroll
    for (int i = 0; i < 4; ++i)
#pragma unroll
        for (int j = 0; j < 4; ++j) { accA[i][j] = zz; accM[i][j] = zz; }

    for (int k0 = 0; k0 < EDIM; k0 += 32) {
        __syncthreads();
        gload16(xhi + xa0 + k0, (char*)Ahi + ldst);
        gload16(xhi + xa1 + k0, (char*)Ahi + 4096 + ldst);
        gload16(xlo + xa0 + k0, (char*)Alo + ldst);
        gload16(xlo + xa1 + k0, (char*)Alo + 4096 + ldst);
        gload16(whi + wa0 + k0, (char*)Bhi + ldst);
        gload16(whi + wa1 + k0, (char*)Bhi + 4096 + ldst);
        gload16(wlo + wa0 + k0, (char*)Blo + ldst);
        gload16(wlo + wa1 + k0, (char*)Blo + 4096 + ldst);
        __syncthreads();   // drains vmcnt(0) for global_load_lds

        f16x8 ah[4], al[4];
#pragma unroll
        for (int mf = 0; mf < 4; ++mf) {
            ah[mf] = *(const f16x8*)((const char*)Ahi + aoff + mf * 1024);
            al[mf] = *(const f16x8*)((const char*)Alo + aoff + mf * 1024);
        }
#pragma unroll
        for (int nf = 0; nf < 4; ++nf) {
            f16x8 bh = *(const f16x8*)((const char*)Bhi + boff + nf * 1024);
            f16x8 bl = *(const f16x8*)((const char*)Blo + boff + nf * 1024);
#pragma unroll
            for (int mf = 0; mf < 4; ++mf) {
                accA[mf][nf] = MFMA16(ah[mf], bh, accA[mf][nf]);
                accM[mf][nf] = MFMA16(ah[mf], bl, accM[mf][nf]);
                accM[mf][nf] = MFMA16(al[mf], bh, accM[mf][nf]);
            }
        }
    }

    float b1r[4], w2r[4][8];
#pragma unroll
    for (int nf = 0; nf < 4; ++nf) {
        int h = h0 + wn * 64 + nf * 16 + lrow;
        b1r[nf] = b1[h];
#pragma unroll
        for (int n = 0; n < 8; ++n) w2r[nf][n] = w2[(size_t)h * NEXP + n];
    }

    const int b0 = l & 1, b1b = (l >> 1) & 1, b2 = (l >> 2) & 1, b3 = (l >> 3) & 1;
    const int regf = (b0 << 1) | b1b;
    const int n0e  = b2 * 4 + b3 * 2;
    float outq[4][2];
    const float SC = 1.0f / 2048.0f;

#pragma unroll
    for (int q = 0; q < 4; ++q) {
        float v[32];
#pragma unroll
        for (int i = 0; i < 32; ++i) v[i] = 0.f;
#pragma unroll
        for (int reg = 0; reg < 4; ++reg)
#pragma unroll
            for (int nf = 0; nf < 4; ++nf) {
                float hval = accA[q][nf][reg] + accM[q][nf][reg] * SC + b1r[nf];
                float hv = fmaxf(hval, 0.f);
#pragma unroll
                for (int n = 0; n < 8; ++n)
                    v[reg * 8 + n] = fmaf(hv, w2r[nf][n], v[reg * 8 + n]);
            }
        float t1[16];
#pragma unroll
        for (int i = 0; i < 16; ++i) {
            float keep = b0 ? v[i + 16] : v[i];
            float send = b0 ? v[i] : v[i + 16];
            t1[i] = keep + __shfl_xor(send, 1);
        }
        float t2[8];
#pragma unroll
        for (int i = 0; i < 8; ++i) {
            float keep = b1b ? t1[i + 8] : t1[i];
            float send = b1b ? t1[i] : t1[i + 8];
            t2[i] = keep + __shfl_xor(send, 2);
        }
        float t3[4];
#pragma unroll
        for (int i = 0; i < 4; ++i) {
            float keep = b2 ? t2[i + 4] : t2[i];
            float send = b2 ? t2[i] : t2[i + 4];
            t3[i] = keep + __shfl_xor(send, 4);
        }
#pragma unroll
        for (int j = 0; j < 2; ++j) {
            float keep = b3 ? t3[j + 2] : t3[j];
            float send = b3 ? t3[j] : t3[j + 2];
            outq[q][j] = keep + __shfl_xor(send, 8);
        }
    }

    __syncthreads();
    float* red = (float*)Ahi;
    if (wn == 1) {
#pragma unroll
        for (int q = 0; q < 4; ++q) {
            red[(wm * 64 + l) * 8 + q * 2 + 0] = outq[q][0];
            red[(wm * 64 + l) * 8 + q * 2 + 1] = outq[q][1];
        }
    }
    __syncthreads();
    if (wn == 0) {
#pragma unroll
        for (int q = 0; q < 4; ++q) {
            float a = outq[q][0] + red[(wm * 64 + l) * 8 + q * 2 + 0];
            float b = outq[q][1] + red[(wm * 64 + l) * 8 + q * 2 + 1];
            int rl = wm * 64 + q * 16 + lslot * 4 + regf;
            *(float2*)&part[((size_t)ht * T_TOK + m0 + rl) * NEXP + n0e] =
                make_float2(a, b);
        }
    }
}

__global__ void zero_counter_kernel(int* c) {
    if (threadIdx.x == 0 && blockIdx.x == 0) *c = 0;
}

// Finish: sum 32 partials (fixed order) + b2, top-2, masked softmax.
// Flags near-tie tokens (min gap < TAU) for exact fp32 recompute.
__global__ __launch_bounds__(256) void router_finish_kernel(
    const float* __restrict__ part, const float* __restrict__ b2,
    float* __restrict__ out, int nparts, int* __restrict__ counter,
    int* __restrict__ list)
{
    int t = blockIdx.x * 256 + threadIdx.x;
    if (t >= T_TOK) return;

    float s[NEXP];
#pragma unroll
    for (int n = 0; n < NEXP; ++n) s[n] = 0.f;
    for (int p = 0; p < nparts; ++p) {
        const float* ps = part + (size_t)p * T_TOK * NEXP + (size_t)t * NEXP;
        float4 v0 = *reinterpret_cast<const float4*>(ps);
        float4 v1 = *reinterpret_cast<const float4*>(ps + 4);
        s[0] += v0.x; s[1] += v0.y; s[2] += v0.z; s[3] += v0.w;
        s[4] += v1.x; s[5] += v1.y; s[6] += v1.z; s[7] += v1.w;
    }
#pragma unroll
    for (int n = 0; n < NEXP; ++n) s[n] += b2[n];

    int i1 = 0; float v1 = s[0];
#pragma unroll
    for (int n = 1; n < NEXP; ++n) { if (s[n] > v1) { v1 = s[n]; i1 = n; } }
    int i2 = -1; float v2 = -3.402823466e38f;
#pragma unroll
    for (int n = 0; n < NEXP; ++n) { if (n != i1 && s[n] > v2) { v2 = s[n]; i2 = n; } }
    float v3 = -3.402823466e38f;
#pragma unroll
    for (int n = 0; n < NEXP; ++n) { if (n != i1 && n != i2 && s[n] > v3) v3 = s[n]; }

    if ((v1 - v2) < TAU || (v2 - v3) < TAU) {
        int pos = atomicAdd(counter, 1);
        list[pos] = t;
    }

    float e2 = expf(v2 - v1);
    float denom = 1.f + e2;
    float p1 = 1.f / denom;
    float p2 = e2 / denom;
#pragma unroll
    for (int n = 0; n < NEXP; ++n)
        out[(size_t)t * NEXP + n] = (n == i1) ? p1 : ((n == i2) ? p2 : 0.f);
    out[(size_t)T_TOK * NEXP + (size_t)t * 2 + 0] = (float)i1;
    out[(size_t)T_TOK * NEXP + (size_t)t * 2 + 1] = (float)i2;
}

// Exact fp32 recompute, stage 1: per (flagged token g, h-range r of 8),
// compute partial expert sums over h in [r*512, r*512+512). Deterministic.
__global__ __launch_bounds__(256) void refine_partial_kernel(
    const float* __restrict__ x, const float* __restrict__ w1,
    const float* __restrict__ b1, const float* __restrict__ w2,
    const int* __restrict__ counter, const int* __restrict__ list,
    float* __restrict__ rpart)
{
    __shared__ float xs[EDIM];
    __shared__ float sred[256][NEXP];
    const int tid = threadIdx.x;
    const int count = *counter;
    const int total = count * 8;

    for (int w = blockIdx.x; w < total; w += gridDim.x) {
        const int g = w >> 3, r = w & 7;
        const int t = list[g];
        for (int i = tid; i < EDIM; i += 256) xs[i] = x[(size_t)t * EDIM + i];
        __syncthreads();

        const int hA = r * 512 + tid;
        const int hB = hA + 256;
        float a0 = 0.f, a1 = 0.f;
#pragma unroll 4
        for (int e = 0; e < EDIM; ++e) {
            float xe = xs[e];
            a0 = fmaf(xe, w1[(size_t)e * HDIM + hA], a0);
            a1 = fmaf(xe, w1[(size_t)e * HDIM + hB], a1);
        }
        float hv0 = fmaxf(a0 + b1[hA], 0.f);
        float hv1 = fmaxf(a1 + b1[hB], 0.f);
        float s[NEXP];
#pragma unroll
        for (int n = 0; n < NEXP; ++n)
            s[n] = hv0 * w2[(size_t)hA * NEXP + n] + hv1 * w2[(size_t)hB * NEXP + n];

#pragma unroll
        for (int n = 0; n < NEXP; ++n) sred[tid][n] = s[n];
        __syncthreads();
        for (int ofs = 128; ofs >= 1; ofs >>= 1) {
            if (tid < ofs)
#pragma unroll
                for (int n = 0; n < NEXP; ++n) sred[tid][n] += sred[tid + ofs][n];
            __syncthreads();
        }
        if (tid < NEXP) rpart[((size_t)g * 8 + r) * NEXP + tid] = sred[0][tid];
        __syncthreads();
    }
}

// Stage 2: combine 8 range-partials per flagged token (fixed order), redo
// top-2 + softmax, overwrite outputs.
__global__ __launch_bounds__(256) void refine_final_kernel(
    const int* __restrict__ counter, const int* __restrict__ list,
    const float* __restrict__ rpart, const float* __restrict__ b2,
    float* __restrict__ out)
{
    const int count = *counter;
    for (int g = blockIdx.x * 256 + threadIdx.x; g < count; g += gridDim.x * 256) {
        const int t = list[g];
        float s[NEXP];
#pragma unroll
        for (int n = 0; n < NEXP; ++n) s[n] = b2[n];
        for (int r = 0; r < 8; ++r)
#pragma unroll
            for (int n = 0; n < NEXP; ++n)
                s[n] += rpart[((size_t)g * 8 + r) * NEXP + n];

        int i1 = 0; float v1 = s[0];
#pragma unroll
        for (int n = 1; n < NEXP; ++n) { if (s[n] > v1) { v1 = s[n]; i1 = n; } }
        int i2 = -1; float v2 = -3.402823466e38f;
#pragma unroll
        for (int n = 0; n < NEXP; ++n) { if (n != i1 && s[n] > v2) { v2 = s[n]; i2 = n; } }

        float e2 = expf(v2 - v1);
        float denom = 1.f + e2;
        float p1 = 1.f / denom;
        float p2 = e2 / denom;
#pragma unroll
        for (int n = 0; n < NEXP; ++n)
            out[(size_t)t * NEXP + n] = (n == i1) ? p1 : ((n == i2) ? p2 : 0.f);
        out[(size_t)T_TOK * NEXP + (size_t)t * 2 + 0] = (float)i1;
        out[(size_t)T_TOK * NEXP + (size_t)t * 2 + 1] = (float)i2;
    }
}

// ===========================================================================
// Fallback (R1 fp32 kernel, passed at 3.2 ms) if workspace too small.
// ===========================================================================
#define BM 128
#define BH 128
#define BK 16
#define NHT (HDIM / BH)

__global__ __launch_bounds__(256) void score_gemm_kernel(
    const float* __restrict__ x, const float* __restrict__ w1,
    const float* __restrict__ b1, const float* __restrict__ w2,
    float* __restrict__ dst)
{
    __shared__ float xs[BK][BM + 4];
    __shared__ float wsh[BK][BH];
    __shared__ float w2s[BH * NEXP];
    __shared__ float b1s[BH];

    const int htile = blockIdx.x;
    const int mtile = blockIdx.y;
    const int h0 = htile * BH;
    const int m0 = mtile * BM;
    const int tid = threadIdx.x;
    const int tx = tid & 15;
    const int ty = tid >> 4;

    {
        float4 v = *reinterpret_cast<const float4*>(&w2[(size_t)h0 * NEXP + tid * 4]);
        *reinterpret_cast<float4*>(&w2s[tid * 4]) = v;
        if (tid < BH) b1s[tid] = b1[h0 + tid];
    }

    float acc[8][8];
#pragma unroll
    for (int i = 0; i < 8; ++i)
#pragma unroll
        for (int j = 0; j < 8; ++j) acc[i][j] = 0.f;

    const int e_off = tid & 15;
    const int t_row = tid >> 4;
    const int h_off = tid & 127;
    const int k_off = tid >> 7;

    for (int k0 = 0; k0 < EDIM; k0 += BK) {
        __syncthreads();
#pragma unroll
        for (int r = 0; r < 8; ++r) {
            int tok = t_row + r * 16;
            xs[e_off][tok] = x[(size_t)(m0 + tok) * EDIM + k0 + e_off];
        }
#pragma unroll
        for (int r = 0; r < 8; ++r) {
            int k = k_off + r * 2;
            wsh[k][h_off] = w1[(size_t)(k0 + k) * HDIM + h0 + h_off];
        }
        __syncthreads();
#pragma unroll
        for (int k = 0; k < BK; ++k) {
            float a[8], b[8];
            *reinterpret_cast<float4*>(&a[0]) = *reinterpret_cast<const float4*>(&xs[k][ty * 8]);
            *reinterpret_cast<float4*>(&a[4]) = *reinterpret_cast<const float4*>(&xs[k][ty * 8 + 4]);
            *reinterpret_cast<float4*>(&b[0]) = *reinterpret_cast<const float4*>(&wsh[k][tx * 8]);
            *reinterpret_cast<float4*>(&b[4]) = *reinterpret_cast<const float4*>(&wsh[k][tx * 8 + 4]);
#pragma unroll
            for (int i = 0; i < 8; ++i)
#pragma unroll
                for (int j = 0; j < 8; ++j)
                    acc[i][j] = fmaf(a[i], b[j], acc[i][j]);
        }
    }

    float sred[8][NEXP];
#pragma unroll
    for (int i = 0; i < 8; ++i) {
        float hv[8];
#pragma unroll
        for (int j = 0; j < 8; ++j)
            hv[j] = fmaxf(acc[i][j] + b1s[tx * 8 + j], 0.f);
#pragma unroll
        for (int n = 0; n < NEXP; ++n) {
            float ssum = 0.f;
#pragma unroll
            for (int j = 0; j < 8; ++j)
                ssum = fmaf(hv[j], w2s[(tx * 8 + j) * NEXP + n], ssum);
            sred[i][n] = ssum;
        }
    }
#pragma unroll
    for (int i = 0; i < 8; ++i)
#pragma unroll
        for (int n = 0; n < NEXP; ++n) {
            float v = sred[i][n];
            v += __shfl_xor(v, 1);
            v += __shfl_xor(v, 2);
            v += __shfl_xor(v, 4);
            v += __shfl_xor(v, 8);
            sred[i][n] = v;
        }

    if (tx == 0) {
        float* slice = dst + (size_t)htile * T_TOK * NEXP;
#pragma unroll
        for (int i = 0; i < 8; ++i)
#pragma unroll
            for (int n = 0; n < NEXP; ++n)
                slice[(size_t)(m0 + ty * 8 + i) * NEXP + n] = sred[i][n];
    }
}

__global__ __launch_bounds__(256) void finish_simple_kernel(
    const float* __restrict__ part, const float* __restrict__ b2,
    float* __restrict__ out, int nparts)
{
    int t = blockIdx.x * 256 + threadIdx.x;
    if (t >= T_TOK) return;
    float s[NEXP];
#pragma unroll
    for (int n = 0; n < NEXP; ++n) s[n] = 0.f;
    for (int p = 0; p < nparts; ++p) {
        const float* ps = part + (size_t)p * T_TOK * NEXP + (size_t)t * NEXP;
        float4 v0 = *reinterpret_cast<const float4*>(ps);
        float4 v1 = *reinterpret_cast<const float4*>(ps + 4);
        s[0] += v0.x; s[1] += v0.y; s[2] += v0.z; s[3] += v0.w;
        s[4] += v1.x; s[5] += v1.y; s[6] += v1.z; s[7] += v1.w;
    }
#pragma unroll
    for (int n = 0; n < NEXP; ++n) s[n] += b2[n];
    int i1 = 0; float v1 = s[0];
#pragma unroll
    for (int n = 1; n < NEXP; ++n) { if (s[n] > v1) { v1 = s[n]; i1 = n; } }
    int i2 = -1; float v2 = -3.402823466e38f;
#pragma unroll
    for (int n = 0; n < NEXP; ++n) { if (n != i1 && s[n] > v2) { v2 = s[n]; i2 = n; } }
    float e2 = expf(v2 - v1);
    float denom = 1.f + e2;
    float p1 = 1.f / denom;
    float p2 = e2 / denom;
#pragma unroll
    for (int n = 0; n < NEXP; ++n)
        out[(size_t)t * NEXP + n] = (n == i1) ? p1 : ((n == i2) ? p2 : 0.f);
    out[(size_t)T_TOK * NEXP + (size_t)t * 2 + 0] = (float)i1;
    out[(size_t)T_TOK * NEXP + (size_t)t * 2 + 1] = (float)i2;
}

extern "C" void kernel_launch(void* const* d_in, const int* in_sizes, int n_in,
                              void* d_out, int out_size, void* d_ws, size_t ws_size,
                              hipStream_t stream)
{
    const float* x  = (const float*)d_in[0];
    const float* w1 = (const float*)d_in[1];
    const float* b1 = (const float*)d_in[2];
    const float* w2 = (const float*)d_in[3];
    const float* b2 = (const float*)d_in[4];
    float* out = (float*)d_out;

    char* ws = (char*)d_ws;
    _Float16* xhi = (_Float16*)ws;                      // 64 MB
    _Float16* xlo = (_Float16*)(ws + 67108864);         // 64 MB
    _Float16* whi = (_Float16*)(ws + 134217728);        // 8 MB
    _Float16* wlo = (_Float16*)(ws + 142606336);        // 8 MB
    float* part   = (float*)(ws + 150994944);           // 32 MB
    // refine scratch aliases xhi (dead after mfma kernel):
    int* counter  = (int*)ws;                           // 4 B
    int* list     = (int*)(ws + 1024);                  // 128 KB
    float* rpart  = (float*)(ws + 1024 + 131072);       // <= 8 MB
    const size_t NEED = 184549376;

    if (ws_size >= NEED) {
        split_x_kernel<<<2048, 256, 0, stream>>>(x, xhi, xlo, (T_TOK * EDIM) / 4);
        dim3 tg(64, 16);
        split_w1t_kernel<<<tg, 256, 0, stream>>>(w1, whi, wlo);
        dim3 gg(32, 256);
        mfma_score_kernel<<<gg, 256, 0, stream>>>(xhi, xlo, whi, wlo, b1, w2, part);
        zero_counter_kernel<<<1, 64, 0, stream>>>(counter);
        router_finish_kernel<<<T_TOK / 256, 256, 0, stream>>>(part, b2, out, 32,
                                                              counter, list);
        refine_partial_kernel<<<256, 256, 0, stream>>>(x, w1, b1, w2, counter,
                                                       list, rpart);
        refine_final_kernel<<<16, 256, 0, stream>>>(counter, list, rpart, b2, out);
    } else {
        float* p1 = (float*)d_ws;  // needs 32 MB
        dim3 grid(NHT, T_TOK / BM);
        score_gemm_kernel<<<grid, 256, 0, stream>>>(x, w1, b1, w2, p1);
        finish_simple_kernel<<<T_TOK / 256, 256, 0, stream>>>(p1, b2, out, NHT);
    }
}

// Round 5
// 671.886 us; speedup vs baseline: 4.7525x; 1.5252x over previous
//
#include <hip/hip_runtime.h>

#define T_TOK 32768
#define EDIM  1024
#define HDIM  4096
#define NEXP  8
#define TAU   1.0e-3f
#define MAXR  8192

// ===========================================================================
// Single-pass fp16 MFMA scorer + exact fp32 refinement of near-tie tokens.
//   score ~= relu(x_f16 @ W1_f16 + b1) @ W2  (fp32 accum; sigma_err ~3e-5)
//   tokens with top-3 gap < TAU (=1e-3, ~30 sigma) are exactly recomputed
//   in fp32 via a tiled mini-GEMM over the gathered flagged tokens.
// ===========================================================================

typedef _Float16 f16x8 __attribute__((ext_vector_type(8)));
typedef _Float16 f16x4 __attribute__((ext_vector_type(4)));
typedef __attribute__((ext_vector_type(4))) float f32x4;
#define MFMA16(a, b, c) __builtin_amdgcn_mfma_f32_16x16x32_f16(a, b, c, 0, 0, 0)

__device__ __forceinline__ void gload16(const void* g, void* l) {
    __builtin_amdgcn_global_load_lds(
        (const __attribute__((address_space(1))) void*)g,
        (__attribute__((address_space(3))) void*)l, 16, 0, 0);
}

__global__ __launch_bounds__(256) void split_x_kernel(
    const float* __restrict__ x, _Float16* __restrict__ hi, int n4)
{
    int i = blockIdx.x * 256 + threadIdx.x;
    int stride = gridDim.x * 256;
    for (; i < n4; i += stride) {
        float4 v = ((const float4*)x)[i];
        f16x4 h;
        h[0] = (_Float16)v.x; h[1] = (_Float16)v.y;
        h[2] = (_Float16)v.z; h[3] = (_Float16)v.w;
        *(f16x4*)&hi[i * 4] = h;
    }
}

// w1 [1024][4096] f32  ->  w1t [4096][1024] fp16 (transposed)
__global__ __launch_bounds__(256) void split_w1t_kernel(
    const float* __restrict__ w1, _Float16* __restrict__ thi)
{
    __shared__ float t[64][65];
    const int ht = blockIdx.x;   // 64 h-tiles
    const int et = blockIdx.y;   // 16 e-tiles
    const int tid = threadIdx.x;
    const int er = tid >> 6, hc = tid & 63;
#pragma unroll
    for (int rr = 0; rr < 16; ++rr) {
        int e = rr * 4 + er;
        t[e][hc] = w1[(size_t)(et * 64 + e) * HDIM + ht * 64 + hc];
    }
    __syncthreads();
    const int hl = tid >> 2, eg = tid & 3;
    size_t base = (size_t)(ht * 64 + hl) * EDIM + et * 64 + eg * 16;
#pragma unroll
    for (int q = 0; q < 4; ++q) {
        f16x4 a;
#pragma unroll
        for (int z = 0; z < 4; ++z) a[z] = (_Float16)t[eg * 16 + q * 4 + z][hl];
        *(f16x4*)&thi[base + q * 4] = a;
    }
}

// Fused MFMA GEMM + relu/bias + W2 fold. Grid (32 htiles, 256 mtiles), 256 thr.
// LDS tiles [128 rows][32 k] fp16, 64B rows; XOR swizzle on 16B slots:
// LDS slot t of row r holds global slot t ^ ((r>>1)&3)  (both-sides, rule #21).
__global__ __launch_bounds__(256, 3) void mfma_score_kernel(
    const _Float16* __restrict__ xhi, const _Float16* __restrict__ whi,
    const float* __restrict__ b1, const float* __restrict__ w2,
    float* __restrict__ part)
{
    __shared__ __align__(16) _Float16 Ahi[128 * 32];
    __shared__ __align__(16) _Float16 Bhi[128 * 32];

    const int ht = blockIdx.x;
    const int m0 = blockIdx.y * 128;
    const int h0 = ht * 128;
    const int tid = threadIdx.x;
    const int l = tid & 63;
    const int wid = tid >> 6;
    const int wm = wid >> 1, wn = wid & 1;

    const int srow = tid >> 2;
    const int sg = (tid & 3) ^ ((srow >> 1) & 3);
    const size_t xa0 = (size_t)(m0 + srow) * EDIM + sg * 8;
    const size_t xa1 = (size_t)(m0 + 64 + srow) * EDIM + sg * 8;
    const size_t wa0 = (size_t)(h0 + srow) * EDIM + sg * 8;
    const size_t wa1 = (size_t)(h0 + 64 + srow) * EDIM + sg * 8;
    const int ldst = tid * 16;

    const int lrow = l & 15, lslot = l >> 4;
    const int rslot = lslot ^ ((lrow >> 1) & 3);
    const int aoff = (wm * 64 + lrow) * 64 + rslot * 16;
    const int boff = (wn * 64 + lrow) * 64 + rslot * 16;

    f32x4 accA[4][4];
    const f32x4 zz = {0.f, 0.f, 0.f, 0.f};
#pragma unroll
    for (int i = 0; i < 4; ++i)
#pragma unroll
        for (int j = 0; j < 4; ++j) accA[i][j] = zz;

    for (int k0 = 0; k0 < EDIM; k0 += 32) {
        __syncthreads();
        gload16(xhi + xa0 + k0, (char*)Ahi + ldst);
        gload16(xhi + xa1 + k0, (char*)Ahi + 4096 + ldst);
        gload16(whi + wa0 + k0, (char*)Bhi + ldst);
        gload16(whi + wa1 + k0, (char*)Bhi + 4096 + ldst);
        __syncthreads();   // drains vmcnt(0) for global_load_lds

        f16x8 ah[4];
#pragma unroll
        for (int mf = 0; mf < 4; ++mf)
            ah[mf] = *(const f16x8*)((const char*)Ahi + aoff + mf * 1024);
#pragma unroll
        for (int nf = 0; nf < 4; ++nf) {
            f16x8 bh = *(const f16x8*)((const char*)Bhi + boff + nf * 1024);
#pragma unroll
            for (int mf = 0; mf < 4; ++mf)
                accA[mf][nf] = MFMA16(ah[mf], bh, accA[mf][nf]);
        }
    }

    float b1r[4], w2r[4][8];
#pragma unroll
    for (int nf = 0; nf < 4; ++nf) {
        int h = h0 + wn * 64 + nf * 16 + lrow;
        b1r[nf] = b1[h];
#pragma unroll
        for (int n = 0; n < 8; ++n) w2r[nf][n] = w2[(size_t)h * NEXP + n];
    }

    const int b0 = l & 1, b1b = (l >> 1) & 1, b2 = (l >> 2) & 1, b3 = (l >> 3) & 1;
    const int regf = (b0 << 1) | b1b;
    const int n0e  = b2 * 4 + b3 * 2;
    float outq[4][2];

#pragma unroll
    for (int q = 0; q < 4; ++q) {
        float v[32];
#pragma unroll
        for (int i = 0; i < 32; ++i) v[i] = 0.f;
#pragma unroll
        for (int reg = 0; reg < 4; ++reg)
#pragma unroll
            for (int nf = 0; nf < 4; ++nf) {
                float hv = fmaxf(accA[q][nf][reg] + b1r[nf], 0.f);
#pragma unroll
                for (int n = 0; n < 8; ++n)
                    v[reg * 8 + n] = fmaf(hv, w2r[nf][n], v[reg * 8 + n]);
            }
        float t1[16];
#pragma unroll
        for (int i = 0; i < 16; ++i) {
            float keep = b0 ? v[i + 16] : v[i];
            float send = b0 ? v[i] : v[i + 16];
            t1[i] = keep + __shfl_xor(send, 1);
        }
        float t2[8];
#pragma unroll
        for (int i = 0; i < 8; ++i) {
            float keep = b1b ? t1[i + 8] : t1[i];
            float send = b1b ? t1[i] : t1[i + 8];
            t2[i] = keep + __shfl_xor(send, 2);
        }
        float t3[4];
#pragma unroll
        for (int i = 0; i < 4; ++i) {
            float keep = b2 ? t2[i + 4] : t2[i];
            float send = b2 ? t2[i] : t2[i + 4];
            t3[i] = keep + __shfl_xor(send, 4);
        }
#pragma unroll
        for (int j = 0; j < 2; ++j) {
            float keep = b3 ? t3[j + 2] : t3[j];
            float send = b3 ? t3[j] : t3[j + 2];
            outq[q][j] = keep + __shfl_xor(send, 8);
        }
    }

    __syncthreads();
    float* red = (float*)Ahi;
    if (wn == 1) {
#pragma unroll
        for (int q = 0; q < 4; ++q) {
            red[(wm * 64 + l) * 8 + q * 2 + 0] = outq[q][0];
            red[(wm * 64 + l) * 8 + q * 2 + 1] = outq[q][1];
        }
    }
    __syncthreads();
    if (wn == 0) {
#pragma unroll
        for (int q = 0; q < 4; ++q) {
            float a = outq[q][0] + red[(wm * 64 + l) * 8 + q * 2 + 0];
            float b = outq[q][1] + red[(wm * 64 + l) * 8 + q * 2 + 1];
            int rl = wm * 64 + q * 16 + lslot * 4 + regf;
            *(float2*)&part[((size_t)ht * T_TOK + m0 + rl) * NEXP + n0e] =
                make_float2(a, b);
        }
    }
}

__global__ void zero_counter_kernel(int* c) {
    if (threadIdx.x == 0 && blockIdx.x == 0) *c = 0;
}

// Finish: sum 32 partials (fixed order) + b2, top-2, masked softmax.
// Flags near-tie tokens (top-3 gap < TAU) for exact fp32 recompute.
__global__ __launch_bounds__(256) void router_finish_kernel(
    const float* __restrict__ part, const float* __restrict__ b2,
    float* __restrict__ out, int nparts, int* __restrict__ counter,
    int* __restrict__ list)
{
    int t = blockIdx.x * 256 + threadIdx.x;
    if (t >= T_TOK) return;

    float s[NEXP];
#pragma unroll
    for (int n = 0; n < NEXP; ++n) s[n] = 0.f;
    for (int p = 0; p < nparts; ++p) {
        const float* ps = part + (size_t)p * T_TOK * NEXP + (size_t)t * NEXP;
        float4 v0 = *reinterpret_cast<const float4*>(ps);
        float4 v1 = *reinterpret_cast<const float4*>(ps + 4);
        s[0] += v0.x; s[1] += v0.y; s[2] += v0.z; s[3] += v0.w;
        s[4] += v1.x; s[5] += v1.y; s[6] += v1.z; s[7] += v1.w;
    }
#pragma unroll
    for (int n = 0; n < NEXP; ++n) s[n] += b2[n];

    int i1 = 0; float v1 = s[0];
#pragma unroll
    for (int n = 1; n < NEXP; ++n) { if (s[n] > v1) { v1 = s[n]; i1 = n; } }
    int i2 = -1; float v2 = -3.402823466e38f;
#pragma unroll
    for (int n = 0; n < NEXP; ++n) { if (n != i1 && s[n] > v2) { v2 = s[n]; i2 = n; } }
    float v3 = -3.402823466e38f;
#pragma unroll
    for (int n = 0; n < NEXP; ++n) { if (n != i1 && n != i2 && s[n] > v3) v3 = s[n]; }

    if ((v1 - v2) < TAU || (v2 - v3) < TAU) {
        int pos = atomicAdd(counter, 1);
        list[pos] = t;
    }

    float e2 = expf(v2 - v1);
    float denom = 1.f + e2;
    float p1 = 1.f / denom;
    float p2 = e2 / denom;
#pragma unroll
    for (int n = 0; n < NEXP; ++n)
        out[(size_t)t * NEXP + n] = (n == i1) ? p1 : ((n == i2) ? p2 : 0.f);
    out[(size_t)T_TOK * NEXP + (size_t)t * 2 + 0] = (float)i1;
    out[(size_t)T_TOK * NEXP + (size_t)t * 2 + 1] = (float)i2;
}

// Gather flagged tokens' x rows into compact xg [cnt][1024].
__global__ __launch_bounds__(256) void gather_x_kernel(
    const float* __restrict__ x, const int* __restrict__ counter,
    const int* __restrict__ list, float* __restrict__ xg)
{
    int cnt = *counter; if (cnt > MAXR) cnt = MAXR;
    for (int g = blockIdx.x; g < cnt; g += gridDim.x) {
        const int t = list[g];
        float4 v = ((const float4*)(x + (size_t)t * EDIM))[threadIdx.x];
        ((float4*)(xg + (size_t)g * EDIM))[threadIdx.x] = v;
    }
}

// Exact fp32 tiled GEMM over flagged tokens: 64(M) x 128(H) tiles.
// Grid (32 htiles, MAXR/64); blocks beyond count exit. Deterministic.
__global__ __launch_bounds__(256) void refine_gemm_kernel(
    const float* __restrict__ xg, const float* __restrict__ w1,
    const float* __restrict__ b1, const float* __restrict__ w2,
    const int* __restrict__ counter, float* __restrict__ rpart)
{
    int cnt = *counter; if (cnt > MAXR) cnt = MAXR;
    const int m0 = blockIdx.y * 64;
    if (m0 >= cnt) return;
    const int ht = blockIdx.x;
    const int h0 = ht * 128;
    const int tid = threadIdx.x;
    const int tx = tid & 15, ty = tid >> 4;

    __shared__ float xs[16][68];
    __shared__ float wsh[16][128];

    float acc[4][8];
#pragma unroll
    for (int i = 0; i < 4; ++i)
#pragma unroll
        for (int j = 0; j < 8; ++j) acc[i][j] = 0.f;

    const int lk = tid & 15, lt = tid >> 4;
    const int lh = tid & 127, lkg = tid >> 7;

    for (int k0 = 0; k0 < EDIM; k0 += 16) {
        __syncthreads();
#pragma unroll
        for (int r = 0; r < 4; ++r)
            xs[lk][lt + r * 16] = xg[(size_t)(m0 + lt + r * 16) * EDIM + k0 + lk];
#pragma unroll
        for (int r = 0; r < 8; ++r)
            wsh[lkg + r * 2][lh] = w1[(size_t)(k0 + lkg + r * 2) * HDIM + h0 + lh];
        __syncthreads();
#pragma unroll
        for (int k = 0; k < 16; ++k) {
            float a[4], b[8];
#pragma unroll
            for (int i = 0; i < 4; ++i) a[i] = xs[k][ty * 4 + i];
            *reinterpret_cast<float4*>(&b[0]) = *reinterpret_cast<const float4*>(&wsh[k][tx * 8]);
            *reinterpret_cast<float4*>(&b[4]) = *reinterpret_cast<const float4*>(&wsh[k][tx * 8 + 4]);
#pragma unroll
            for (int i = 0; i < 4; ++i)
#pragma unroll
                for (int j = 0; j < 8; ++j)
                    acc[i][j] = fmaf(a[i], b[j], acc[i][j]);
        }
    }

    float sred[4][NEXP];
#pragma unroll
    for (int i = 0; i < 4; ++i) {
        float hv[8];
#pragma unroll
        for (int j = 0; j < 8; ++j)
            hv[j] = fmaxf(acc[i][j] + b1[h0 + tx * 8 + j], 0.f);
#pragma unroll
        for (int n = 0; n < NEXP; ++n) {
            float ssum = 0.f;
#pragma unroll
            for (int j = 0; j < 8; ++j)
                ssum = fmaf(hv[j], w2[(size_t)(h0 + tx * 8 + j) * NEXP + n], ssum);
            sred[i][n] = ssum;
        }
    }
#pragma unroll
    for (int i = 0; i < 4; ++i)
#pragma unroll
        for (int n = 0; n < NEXP; ++n) {
            float v = sred[i][n];
            v += __shfl_xor(v, 1);
            v += __shfl_xor(v, 2);
            v += __shfl_xor(v, 4);
            v += __shfl_xor(v, 8);
            sred[i][n] = v;
        }

    if (tx == 0) {
#pragma unroll
        for (int i = 0; i < 4; ++i) {
            int g = m0 + ty * 4 + i;
            if (g < cnt) {
#pragma unroll
                for (int n = 0; n < NEXP; ++n)
                    rpart[((size_t)g * 32 + ht) * NEXP + n] = sred[i][n];
            }
        }
    }
}

// Combine 32 htile partials per flagged token (fixed order); redo top-2.
__global__ __launch_bounds__(256) void refine_final_kernel(
    const int* __restrict__ counter, const int* __restrict__ list,
    const float* __restrict__ rpart, const float* __restrict__ b2,
    float* __restrict__ out)
{
    int cnt = *counter; if (cnt > MAXR) cnt = MAXR;
    const int g = blockIdx.x * 256 + threadIdx.x;
    if (g >= cnt) return;
    const int t = list[g];
    float s[NEXP];
#pragma unroll
    for (int n = 0; n < NEXP; ++n) s[n] = b2[n];
    for (int r = 0; r < 32; ++r)
#pragma unroll
        for (int n = 0; n < NEXP; ++n)
            s[n] += rpart[((size_t)g * 32 + r) * NEXP + n];

    int i1 = 0; float v1 = s[0];
#pragma unroll
    for (int n = 1; n < NEXP; ++n) { if (s[n] > v1) { v1 = s[n]; i1 = n; } }
    int i2 = -1; float v2 = -3.402823466e38f;
#pragma unroll
    for (int n = 0; n < NEXP; ++n) { if (n != i1 && s[n] > v2) { v2 = s[n]; i2 = n; } }

    float e2 = expf(v2 - v1);
    float denom = 1.f + e2;
    float p1 = 1.f / denom;
    float p2 = e2 / denom;
#pragma unroll
    for (int n = 0; n < NEXP; ++n)
        out[(size_t)t * NEXP + n] = (n == i1) ? p1 : ((n == i2) ? p2 : 0.f);
    out[(size_t)T_TOK * NEXP + (size_t)t * 2 + 0] = (float)i1;
    out[(size_t)T_TOK * NEXP + (size_t)t * 2 + 1] = (float)i2;
}

// ===========================================================================
// Fallback (R1 fp32 kernel, passed at 3.2 ms) if workspace too small.
// ===========================================================================
#define BM 128
#define BH 128
#define BK 16
#define NHT (HDIM / BH)

__global__ __launch_bounds__(256) void score_gemm_kernel(
    const float* __restrict__ x, const float* __restrict__ w1,
    const float* __restrict__ b1, const float* __restrict__ w2,
    float* __restrict__ dst)
{
    __shared__ float xs[BK][BM + 4];
    __shared__ float wsh[BK][BH];
    __shared__ float w2s[BH * NEXP];
    __shared__ float b1s[BH];

    const int htile = blockIdx.x;
    const int mtile = blockIdx.y;
    const int h0 = htile * BH;
    const int m0 = mtile * BM;
    const int tid = threadIdx.x;
    const int tx = tid & 15;
    const int ty = tid >> 4;

    {
        float4 v = *reinterpret_cast<const float4*>(&w2[(size_t)h0 * NEXP + tid * 4]);
        *reinterpret_cast<float4*>(&w2s[tid * 4]) = v;
        if (tid < BH) b1s[tid] = b1[h0 + tid];
    }

    float acc[8][8];
#pragma unroll
    for (int i = 0; i < 8; ++i)
#pragma unroll
        for (int j = 0; j < 8; ++j) acc[i][j] = 0.f;

    const int e_off = tid & 15;
    const int t_row = tid >> 4;
    const int h_off = tid & 127;
    const int k_off = tid >> 7;

    for (int k0 = 0; k0 < EDIM; k0 += BK) {
        __syncthreads();
#pragma unroll
        for (int r = 0; r < 8; ++r) {
            int tok = t_row + r * 16;
            xs[e_off][tok] = x[(size_t)(m0 + tok) * EDIM + k0 + e_off];
        }
#pragma unroll
        for (int r = 0; r < 8; ++r) {
            int k = k_off + r * 2;
            wsh[k][h_off] = w1[(size_t)(k0 + k) * HDIM + h0 + h_off];
        }
        __syncthreads();
#pragma unroll
        for (int k = 0; k < BK; ++k) {
            float a[8], b[8];
            *reinterpret_cast<float4*>(&a[0]) = *reinterpret_cast<const float4*>(&xs[k][ty * 8]);
            *reinterpret_cast<float4*>(&a[4]) = *reinterpret_cast<const float4*>(&xs[k][ty * 8 + 4]);
            *reinterpret_cast<float4*>(&b[0]) = *reinterpret_cast<const float4*>(&wsh[k][tx * 8]);
            *reinterpret_cast<float4*>(&b[4]) = *reinterpret_cast<const float4*>(&wsh[k][tx * 8 + 4]);
#pragma unroll
            for (int i = 0; i < 8; ++i)
#pragma unroll
                for (int j = 0; j < 8; ++j)
                    acc[i][j] = fmaf(a[i], b[j], acc[i][j]);
        }
    }

    float sred[8][NEXP];
#pragma unroll
    for (int i = 0; i < 8; ++i) {
        float hv[8];
#pragma unroll
        for (int j = 0; j < 8; ++j)
            hv[j] = fmaxf(acc[i][j] + b1s[tx * 8 + j], 0.f);
#pragma unroll
        for (int n = 0; n < NEXP; ++n) {
            float ssum = 0.f;
#pragma unroll
            for (int j = 0; j < 8; ++j)
                ssum = fmaf(hv[j], w2s[(tx * 8 + j) * NEXP + n], ssum);
            sred[i][n] = ssum;
        }
    }
#pragma unroll
    for (int i = 0; i < 8; ++i)
#pragma unroll
        for (int n = 0; n < NEXP; ++n) {
            float v = sred[i][n];
            v += __shfl_xor(v, 1);
            v += __shfl_xor(v, 2);
            v += __shfl_xor(v, 4);
            v += __shfl_xor(v, 8);
            sred[i][n] = v;
        }

    if (tx == 0) {
        float* slice = dst + (size_t)htile * T_TOK * NEXP;
#pragma unroll
        for (int i = 0; i < 8; ++i)
#pragma unroll
            for (int n = 0; n < NEXP; ++n)
                slice[(size_t)(m0 + ty * 8 + i) * NEXP + n] = sred[i][n];
    }
}

__global__ __launch_bounds__(256) void finish_simple_kernel(
    const float* __restrict__ part, const float* __restrict__ b2,
    float* __restrict__ out, int nparts)
{
    int t = blockIdx.x * 256 + threadIdx.x;
    if (t >= T_TOK) return;
    float s[NEXP];
#pragma unroll
    for (int n = 0; n < NEXP; ++n) s[n] = 0.f;
    for (int p = 0; p < nparts; ++p) {
        const float* ps = part + (size_t)p * T_TOK * NEXP + (size_t)t * NEXP;
        float4 v0 = *reinterpret_cast<const float4*>(ps);
        float4 v1 = *reinterpret_cast<const float4*>(ps + 4);
        s[0] += v0.x; s[1] += v0.y; s[2] += v0.z; s[3] += v0.w;
        s[4] += v1.x; s[5] += v1.y; s[6] += v1.z; s[7] += v1.w;
    }
#pragma unroll
    for (int n = 0; n < NEXP; ++n) s[n] += b2[n];
    int i1 = 0; float v1 = s[0];
#pragma unroll
    for (int n = 1; n < NEXP; ++n) { if (s[n] > v1) { v1 = s[n]; i1 = n; } }
    int i2 = -1; float v2 = -3.402823466e38f;
#pragma unroll
    for (int n = 0; n < NEXP; ++n) { if (n != i1 && s[n] > v2) { v2 = s[n]; i2 = n; } }
    float e2 = expf(v2 - v1);
    float denom = 1.f + e2;
    float p1 = 1.f / denom;
    float p2 = e2 / denom;
#pragma unroll
    for (int n = 0; n < NEXP; ++n)
        out[(size_t)t * NEXP + n] = (n == i1) ? p1 : ((n == i2) ? p2 : 0.f);
    out[(size_t)T_TOK * NEXP + (size_t)t * 2 + 0] = (float)i1;
    out[(size_t)T_TOK * NEXP + (size_t)t * 2 + 1] = (float)i2;
}

extern "C" void kernel_launch(void* const* d_in, const int* in_sizes, int n_in,
                              void* d_out, int out_size, void* d_ws, size_t ws_size,
                              hipStream_t stream)
{
    const float* x  = (const float*)d_in[0];
    const float* w1 = (const float*)d_in[1];
    const float* b1 = (const float*)d_in[2];
    const float* w2 = (const float*)d_in[3];
    const float* b2 = (const float*)d_in[4];
    float* out = (float*)d_out;

    char* ws = (char*)d_ws;
    _Float16* xhi = (_Float16*)ws;                      // 64 MB @ 0
    _Float16* whi = (_Float16*)(ws + 67108864);         //  8 MB @ 64M
    float* part   = (float*)(ws + 75497472);            // 32 MB @ 72M
    int* counter  = (int*)(ws + 109051904);             //  4 B (+pad)
    int* list     = (int*)(ws + 109052928);             // 128 KB
    float* xg     = (float*)(ws + 109184000);           // 32 MB
    float* rpart  = (float*)(ws + 142738432);           //  8 MB -> ends ~144 MB
    const size_t NEED = 151127040;

    if (ws_size >= NEED) {
        split_x_kernel<<<2048, 256, 0, stream>>>(x, xhi, (T_TOK * EDIM) / 4);
        dim3 tg(64, 16);
        split_w1t_kernel<<<tg, 256, 0, stream>>>(w1, whi);
        dim3 gg(32, 256);
        mfma_score_kernel<<<gg, 256, 0, stream>>>(xhi, whi, b1, w2, part);
        zero_counter_kernel<<<1, 64, 0, stream>>>(counter);
        router_finish_kernel<<<T_TOK / 256, 256, 0, stream>>>(part, b2, out, 32,
                                                              counter, list);
        gather_x_kernel<<<256, 256, 0, stream>>>(x, counter, list, xg);
        dim3 rg(32, MAXR / 64);
        refine_gemm_kernel<<<rg, 256, 0, stream>>>(xg, w1, b1, w2, counter, rpart);
        refine_final_kernel<<<MAXR / 256, 256, 0, stream>>>(counter, list, rpart,
                                                            b2, out);
    } else {
        float* p1 = (float*)d_ws;  // needs 32 MB
        dim3 grid(NHT, T_TOK / BM);
        score_gemm_kernel<<<grid, 256, 0, stream>>>(x, w1, b1, w2, p1);
        finish_simple_kernel<<<T_TOK / 256, 256, 0, stream>>>(p1, b2, out, NHT);
    }
}

// Round 6
// 609.152 us; speedup vs baseline: 5.2420x; 1.1030x over previous
//
#include <hip/hip_runtime.h>

#define T_TOK 32768
#define EDIM  1024
#define HDIM  4096
#define NEXP  8
#define TAU   1.0e-3f
#define MAXR  8192

// ===========================================================================
// Single-pass fp16 MFMA scorer (3-stage ring-buffered, counted vmcnt) +
// exact fp32 refinement of near-tie tokens (top-3 gap < TAU).
// ===========================================================================

typedef _Float16 f16x8 __attribute__((ext_vector_type(8)));
typedef _Float16 f16x4 __attribute__((ext_vector_type(4)));
typedef __attribute__((ext_vector_type(4))) float f32x4;
#define MFMA16(a, b, c) __builtin_amdgcn_mfma_f32_16x16x32_f16(a, b, c, 0, 0, 0)

__device__ __forceinline__ void gload16(const void* g, void* l) {
    __builtin_amdgcn_global_load_lds(
        (const __attribute__((address_space(1))) void*)g,
        (__attribute__((address_space(3))) void*)l, 16, 0, 0);
}

__global__ __launch_bounds__(256) void split_x_kernel(
    const float* __restrict__ x, _Float16* __restrict__ hi, int n4)
{
    int i = blockIdx.x * 256 + threadIdx.x;
    int stride = gridDim.x * 256;
    for (; i < n4; i += stride) {
        float4 v = ((const float4*)x)[i];
        f16x4 h;
        h[0] = (_Float16)v.x; h[1] = (_Float16)v.y;
        h[2] = (_Float16)v.z; h[3] = (_Float16)v.w;
        *(f16x4*)&hi[i * 4] = h;
    }
}

// w1 [1024][4096] f32  ->  w1t [4096][1024] fp16 (transposed)
__global__ __launch_bounds__(256) void split_w1t_kernel(
    const float* __restrict__ w1, _Float16* __restrict__ thi)
{
    __shared__ float t[64][65];
    const int ht = blockIdx.x;   // 64 h-tiles
    const int et = blockIdx.y;   // 16 e-tiles
    const int tid = threadIdx.x;
    const int er = tid >> 6, hc = tid & 63;
#pragma unroll
    for (int rr = 0; rr < 16; ++rr) {
        int e = rr * 4 + er;
        t[e][hc] = w1[(size_t)(et * 64 + e) * HDIM + ht * 64 + hc];
    }
    __syncthreads();
    const int hl = tid >> 2, eg = tid & 3;
    size_t base = (size_t)(ht * 64 + hl) * EDIM + et * 64 + eg * 16;
#pragma unroll
    for (int q = 0; q < 4; ++q) {
        f16x4 a;
#pragma unroll
        for (int z = 0; z < 4; ++z) a[z] = (_Float16)t[eg * 16 + q * 4 + z][hl];
        *(f16x4*)&thi[base + q * 4] = a;
    }
}

// Fused MFMA GEMM + relu/bias + W2 fold.
// 128(M)x128(H) tile, BK=32, 3-stage LDS ring, stage t+2 issued during step t,
// s_waitcnt vmcnt(4) (counted; one stage = 4 gload16/thread) + raw s_barrier.
// XOR swizzle on 16B slots (pre-swizzled source + swizzled read, rule #21).
// Grid: 8192 1D, XCD-chunked: chunk c (=bid%8) covers htiles 4c..4c+3.
__global__ __launch_bounds__(256, 3) void mfma_score_kernel(
    const _Float16* __restrict__ xhi, const _Float16* __restrict__ whi,
    const float* __restrict__ b1, const float* __restrict__ w2,
    float* __restrict__ part)
{
    __shared__ __align__(16) _Float16 A3[3 * 4096];  // 3 stages x 8KB
    __shared__ __align__(16) _Float16 B3[3 * 4096];

    const int bid = blockIdx.x;
    const int lg  = (bid & 7) * 1024 + (bid >> 3);   // bijective (8192 % 8 == 0)
    const int ht  = (lg >> 10) * 4 + (lg & 3);
    const int mt  = (lg & 1023) >> 2;
    const int m0 = mt * 128;
    const int h0 = ht * 128;
    const int tid = threadIdx.x;
    const int l = tid & 63;
    const int wid = tid >> 6;
    const int wm = wid >> 1, wn = wid & 1;

    const int srow = tid >> 2;
    const int sg = (tid & 3) ^ ((srow >> 1) & 3);
    const size_t xa0 = (size_t)(m0 + srow) * EDIM + sg * 8;
    const size_t xa1 = (size_t)(m0 + 64 + srow) * EDIM + sg * 8;
    const size_t wa0 = (size_t)(h0 + srow) * EDIM + sg * 8;
    const size_t wa1 = (size_t)(h0 + 64 + srow) * EDIM + sg * 8;
    const int ldst = tid * 16;

    const int lrow = l & 15, lslot = l >> 4;
    const int rslot = lslot ^ ((lrow >> 1) & 3);
    const int aoff = (wm * 64 + lrow) * 64 + rslot * 16;
    const int boff = (wn * 64 + lrow) * 64 + rslot * 16;

    f32x4 accA[4][4];
    const f32x4 zz = {0.f, 0.f, 0.f, 0.f};
#pragma unroll
    for (int i = 0; i < 4; ++i)
#pragma unroll
        for (int j = 0; j < 4; ++j) accA[i][j] = zz;

    auto stage = [&](int s, int bb) {
        const int k0 = s * 32;
        gload16(xhi + xa0 + k0, (char*)A3 + bb * 8192 + ldst);
        gload16(xhi + xa1 + k0, (char*)A3 + bb * 8192 + 4096 + ldst);
        gload16(whi + wa0 + k0, (char*)B3 + bb * 8192 + ldst);
        gload16(whi + wa1 + k0, (char*)B3 + bb * 8192 + 4096 + ldst);
    };
    auto compute = [&](int bb) {
        const char* Ab = (const char*)A3 + bb * 8192;
        const char* Bb = (const char*)B3 + bb * 8192;
        f16x8 ah[4];
#pragma unroll
        for (int mf = 0; mf < 4; ++mf)
            ah[mf] = *(const f16x8*)(Ab + aoff + mf * 1024);
        __builtin_amdgcn_s_setprio(1);
#pragma unroll
        for (int nf = 0; nf < 4; ++nf) {
            f16x8 bh = *(const f16x8*)(Bb + boff + nf * 1024);
#pragma unroll
            for (int mf = 0; mf < 4; ++mf)
                accA[mf][nf] = MFMA16(ah[mf], bh, accA[mf][nf]);
        }
        __builtin_amdgcn_s_setprio(0);
    };

#define WAITV4 do { asm volatile("s_waitcnt vmcnt(4)" ::: "memory"); \
                    __builtin_amdgcn_sched_barrier(0); } while (0)
#define WAITV0 do { asm volatile("s_waitcnt vmcnt(0)" ::: "memory"); \
                    __builtin_amdgcn_sched_barrier(0); } while (0)
#define BARR   do { __builtin_amdgcn_s_barrier(); \
                    __builtin_amdgcn_sched_barrier(0); } while (0)

    // prologue: stages 0 and 1 in flight
    stage(0, 0);
    stage(1, 1);

    // steps 0..29 (each: wait oldest stage, barrier, issue t+2, compute t)
    for (int t = 0; t < 30; t += 3) {
        WAITV4; BARR; stage(t + 2, (t + 2) % 3); compute(0);
        WAITV4; BARR; stage(t + 3, (t + 3) % 3); compute(1);
        WAITV4; BARR; stage(t + 4, (t + 4) % 3); compute(2);
    }
    // step 30: compute buf0 (stage 30), stage 31 still in flight
    WAITV4; BARR; compute(0);
    // step 31: compute buf1 (stage 31)
    WAITV0; BARR; compute(1);

#undef WAITV4
#undef WAITV0
#undef BARR

    // ---- epilogue: bias+relu+W2 fold, reduce over 16 col-lanes ----
    float b1r[4], w2r[4][8];
#pragma unroll
    for (int nf = 0; nf < 4; ++nf) {
        int h = h0 + wn * 64 + nf * 16 + lrow;
        b1r[nf] = b1[h];
#pragma unroll
        for (int n = 0; n < 8; ++n) w2r[nf][n] = w2[(size_t)h * NEXP + n];
    }

    const int b0 = l & 1, b1b = (l >> 1) & 1, b2 = (l >> 2) & 1, b3 = (l >> 3) & 1;
    const int regf = (b0 << 1) | b1b;
    const int n0e  = b2 * 4 + b3 * 2;
    float outq[4][2];

#pragma unroll
    for (int q = 0; q < 4; ++q) {
        float v[32];
#pragma unroll
        for (int i = 0; i < 32; ++i) v[i] = 0.f;
#pragma unroll
        for (int reg = 0; reg < 4; ++reg)
#pragma unroll
            for (int nf = 0; nf < 4; ++nf) {
                float hv = fmaxf(accA[q][nf][reg] + b1r[nf], 0.f);
#pragma unroll
                for (int n = 0; n < 8; ++n)
                    v[reg * 8 + n] = fmaf(hv, w2r[nf][n], v[reg * 8 + n]);
            }
        float t1[16];
#pragma unroll
        for (int i = 0; i < 16; ++i) {
            float keep = b0 ? v[i + 16] : v[i];
            float send = b0 ? v[i] : v[i + 16];
            t1[i] = keep + __shfl_xor(send, 1);
        }
        float t2[8];
#pragma unroll
        for (int i = 0; i < 8; ++i) {
            float keep = b1b ? t1[i + 8] : t1[i];
            float send = b1b ? t1[i] : t1[i + 8];
            t2[i] = keep + __shfl_xor(send, 2);
        }
        float t3[4];
#pragma unroll
        for (int i = 0; i < 4; ++i) {
            float keep = b2 ? t2[i + 4] : t2[i];
            float send = b2 ? t2[i] : t2[i + 4];
            t3[i] = keep + __shfl_xor(send, 4);
        }
#pragma unroll
        for (int j = 0; j < 2; ++j) {
            float keep = b3 ? t3[j + 2] : t3[j];
            float send = b3 ? t3[j] : t3[j + 2];
            outq[q][j] = keep + __shfl_xor(send, 8);
        }
    }

    __syncthreads();
    float* red = (float*)A3;
    if (wn == 1) {
#pragma unroll
        for (int q = 0; q < 4; ++q) {
            red[(wm * 64 + l) * 8 + q * 2 + 0] = outq[q][0];
            red[(wm * 64 + l) * 8 + q * 2 + 1] = outq[q][1];
        }
    }
    __syncthreads();
    if (wn == 0) {
#pragma unroll
        for (int q = 0; q < 4; ++q) {
            float a = outq[q][0] + red[(wm * 64 + l) * 8 + q * 2 + 0];
            float b = outq[q][1] + red[(wm * 64 + l) * 8 + q * 2 + 1];
            int rl = wm * 64 + q * 16 + lslot * 4 + regf;
            *(float2*)&part[((size_t)ht * T_TOK + m0 + rl) * NEXP + n0e] =
                make_float2(a, b);
        }
    }
}

__global__ void zero_counter_kernel(int* c) {
    if (threadIdx.x == 0 && blockIdx.x == 0) *c = 0;
}

// Finish: sum 32 partials (fixed order) + b2, top-2, masked softmax.
// Flags near-tie tokens (top-3 gap < TAU) for exact fp32 recompute.
__global__ __launch_bounds__(256) void router_finish_kernel(
    const float* __restrict__ part, const float* __restrict__ b2,
    float* __restrict__ out, int nparts, int* __restrict__ counter,
    int* __restrict__ list)
{
    int t = blockIdx.x * 256 + threadIdx.x;
    if (t >= T_TOK) return;

    float s[NEXP];
#pragma unroll
    for (int n = 0; n < NEXP; ++n) s[n] = 0.f;
    for (int p = 0; p < nparts; ++p) {
        const float* ps = part + (size_t)p * T_TOK * NEXP + (size_t)t * NEXP;
        float4 v0 = *reinterpret_cast<const float4*>(ps);
        float4 v1 = *reinterpret_cast<const float4*>(ps + 4);
        s[0] += v0.x; s[1] += v0.y; s[2] += v0.z; s[3] += v0.w;
        s[4] += v1.x; s[5] += v1.y; s[6] += v1.z; s[7] += v1.w;
    }
#pragma unroll
    for (int n = 0; n < NEXP; ++n) s[n] += b2[n];

    int i1 = 0; float v1 = s[0];
#pragma unroll
    for (int n = 1; n < NEXP; ++n) { if (s[n] > v1) { v1 = s[n]; i1 = n; } }
    int i2 = -1; float v2 = -3.402823466e38f;
#pragma unroll
    for (int n = 0; n < NEXP; ++n) { if (n != i1 && s[n] > v2) { v2 = s[n]; i2 = n; } }
    float v3 = -3.402823466e38f;
#pragma unroll
    for (int n = 0; n < NEXP; ++n) { if (n != i1 && n != i2 && s[n] > v3) v3 = s[n]; }

    if ((v1 - v2) < TAU || (v2 - v3) < TAU) {
        int pos = atomicAdd(counter, 1);
        list[pos] = t;
    }

    float e2 = expf(v2 - v1);
    float denom = 1.f + e2;
    float p1 = 1.f / denom;
    float p2 = e2 / denom;
#pragma unroll
    for (int n = 0; n < NEXP; ++n)
        out[(size_t)t * NEXP + n] = (n == i1) ? p1 : ((n == i2) ? p2 : 0.f);
    out[(size_t)T_TOK * NEXP + (size_t)t * 2 + 0] = (float)i1;
    out[(size_t)T_TOK * NEXP + (size_t)t * 2 + 1] = (float)i2;
}

// Gather flagged tokens' x rows into compact xg [cnt][1024].
__global__ __launch_bounds__(256) void gather_x_kernel(
    const float* __restrict__ x, const int* __restrict__ counter,
    const int* __restrict__ list, float* __restrict__ xg)
{
    int cnt = *counter; if (cnt > MAXR) cnt = MAXR;
    for (int g = blockIdx.x; g < cnt; g += gridDim.x) {
        const int t = list[g];
        float4 v = ((const float4*)(x + (size_t)t * EDIM))[threadIdx.x];
        ((float4*)(xg + (size_t)g * EDIM))[threadIdx.x] = v;
    }
}

// Exact fp32 tiled GEMM over flagged tokens: 64(M) x 128(H) tiles.
__global__ __launch_bounds__(256) void refine_gemm_kernel(
    const float* __restrict__ xg, const float* __restrict__ w1,
    const float* __restrict__ b1, const float* __restrict__ w2,
    const int* __restrict__ counter, float* __restrict__ rpart)
{
    int cnt = *counter; if (cnt > MAXR) cnt = MAXR;
    const int m0 = blockIdx.y * 64;
    if (m0 >= cnt) return;
    const int ht = blockIdx.x;
    const int h0 = ht * 128;
    const int tid = threadIdx.x;
    const int tx = tid & 15, ty = tid >> 4;

    __shared__ float xs[16][68];
    __shared__ float wsh[16][128];

    float acc[4][8];
#pragma unroll
    for (int i = 0; i < 4; ++i)
#pragma unroll
        for (int j = 0; j < 8; ++j) acc[i][j] = 0.f;

    const int lk = tid & 15, lt = tid >> 4;
    const int lh = tid & 127, lkg = tid >> 7;

    for (int k0 = 0; k0 < EDIM; k0 += 16) {
        __syncthreads();
#pragma unroll
        for (int r = 0; r < 4; ++r)
            xs[lk][lt + r * 16] = xg[(size_t)(m0 + lt + r * 16) * EDIM + k0 + lk];
#pragma unroll
        for (int r = 0; r < 8; ++r)
            wsh[lkg + r * 2][lh] = w1[(size_t)(k0 + lkg + r * 2) * HDIM + h0 + lh];
        __syncthreads();
#pragma unroll
        for (int k = 0; k < 16; ++k) {
            float a[4], b[8];
#pragma unroll
            for (int i = 0; i < 4; ++i) a[i] = xs[k][ty * 4 + i];
            *reinterpret_cast<float4*>(&b[0]) = *reinterpret_cast<const float4*>(&wsh[k][tx * 8]);
            *reinterpret_cast<float4*>(&b[4]) = *reinterpret_cast<const float4*>(&wsh[k][tx * 8 + 4]);
#pragma unroll
            for (int i = 0; i < 4; ++i)
#pragma unroll
                for (int j = 0; j < 8; ++j)
                    acc[i][j] = fmaf(a[i], b[j], acc[i][j]);
        }
    }

    float sred[4][NEXP];
#pragma unroll
    for (int i = 0; i < 4; ++i) {
        float hv[8];
#pragma unroll
        for (int j = 0; j < 8; ++j)
            hv[j] = fmaxf(acc[i][j] + b1[h0 + tx * 8 + j], 0.f);
#pragma unroll
        for (int n = 0; n < NEXP; ++n) {
            float ssum = 0.f;
#pragma unroll
            for (int j = 0; j < 8; ++j)
                ssum = fmaf(hv[j], w2[(size_t)(h0 + tx * 8 + j) * NEXP + n], ssum);
            sred[i][n] = ssum;
        }
    }
#pragma unroll
    for (int i = 0; i < 4; ++i)
#pragma unroll
        for (int n = 0; n < NEXP; ++n) {
            float v = sred[i][n];
            v += __shfl_xor(v, 1);
            v += __shfl_xor(v, 2);
            v += __shfl_xor(v, 4);
            v += __shfl_xor(v, 8);
            sred[i][n] = v;
        }

    if (tx == 0) {
#pragma unroll
        for (int i = 0; i < 4; ++i) {
            int g = m0 + ty * 4 + i;
            if (g < cnt) {
#pragma unroll
                for (int n = 0; n < NEXP; ++n)
                    rpart[((size_t)g * 32 + ht) * NEXP + n] = sred[i][n];
            }
        }
    }
}

// Combine 32 htile partials per flagged token (fixed order); redo top-2.
__global__ __launch_bounds__(256) void refine_final_kernel(
    const int* __restrict__ counter, const int* __restrict__ list,
    const float* __restrict__ rpart, const float* __restrict__ b2,
    float* __restrict__ out)
{
    int cnt = *counter; if (cnt > MAXR) cnt = MAXR;
    const int g = blockIdx.x * 256 + threadIdx.x;
    if (g >= cnt) return;
    const int t = list[g];
    float s[NEXP];
#pragma unroll
    for (int n = 0; n < NEXP; ++n) s[n] = b2[n];
    for (int r = 0; r < 32; ++r)
#pragma unroll
        for (int n = 0; n < NEXP; ++n)
            s[n] += rpart[((size_t)g * 32 + r) * NEXP + n];

    int i1 = 0; float v1 = s[0];
#pragma unroll
    for (int n = 1; n < NEXP; ++n) { if (s[n] > v1) { v1 = s[n]; i1 = n; } }
    int i2 = -1; float v2 = -3.402823466e38f;
#pragma unroll
    for (int n = 0; n < NEXP; ++n) { if (n != i1 && s[n] > v2) { v2 = s[n]; i2 = n; } }

    float e2 = expf(v2 - v1);
    float denom = 1.f + e2;
    float p1 = 1.f / denom;
    float p2 = e2 / denom;
#pragma unroll
    for (int n = 0; n < NEXP; ++n)
        out[(size_t)t * NEXP + n] = (n == i1) ? p1 : ((n == i2) ? p2 : 0.f);
    out[(size_t)T_TOK * NEXP + (size_t)t * 2 + 0] = (float)i1;
    out[(size_t)T_TOK * NEXP + (size_t)t * 2 + 1] = (float)i2;
}

// ===========================================================================
// Fallback (R1 fp32 kernel) if workspace too small.
// ===========================================================================
#define BM 128
#define BH 128
#define BK 16
#define NHT (HDIM / BH)

__global__ __launch_bounds__(256) void score_gemm_kernel(
    const float* __restrict__ x, const float* __restrict__ w1,
    const float* __restrict__ b1, const float* __restrict__ w2,
    float* __restrict__ dst)
{
    __shared__ float xs[BK][BM + 4];
    __shared__ float wsh[BK][BH];
    __shared__ float w2s[BH * NEXP];
    __shared__ float b1s[BH];

    const int htile = blockIdx.x;
    const int mtile = blockIdx.y;
    const int h0 = htile * BH;
    const int m0 = mtile * BM;
    const int tid = threadIdx.x;
    const int tx = tid & 15;
    const int ty = tid >> 4;

    {
        float4 v = *reinterpret_cast<const float4*>(&w2[(size_t)h0 * NEXP + tid * 4]);
        *reinterpret_cast<float4*>(&w2s[tid * 4]) = v;
        if (tid < BH) b1s[tid] = b1[h0 + tid];
    }

    float acc[8][8];
#pragma unroll
    for (int i = 0; i < 8; ++i)
#pragma unroll
        for (int j = 0; j < 8; ++j) acc[i][j] = 0.f;

    const int e_off = tid & 15;
    const int t_row = tid >> 4;
    const int h_off = tid & 127;
    const int k_off = tid >> 7;

    for (int k0 = 0; k0 < EDIM; k0 += BK) {
        __syncthreads();
#pragma unroll
        for (int r = 0; r < 8; ++r) {
            int tok = t_row + r * 16;
            xs[e_off][tok] = x[(size_t)(m0 + tok) * EDIM + k0 + e_off];
        }
#pragma unroll
        for (int r = 0; r < 8; ++r) {
            int k = k_off + r * 2;
            wsh[k][h_off] = w1[(size_t)(k0 + k) * HDIM + h0 + h_off];
        }
        __syncthreads();
#pragma unroll
        for (int k = 0; k < BK; ++k) {
            float a[8], b[8];
            *reinterpret_cast<float4*>(&a[0]) = *reinterpret_cast<const float4*>(&xs[k][ty * 8]);
            *reinterpret_cast<float4*>(&a[4]) = *reinterpret_cast<const float4*>(&xs[k][ty * 8 + 4]);
            *reinterpret_cast<float4*>(&b[0]) = *reinterpret_cast<const float4*>(&wsh[k][tx * 8]);
            *reinterpret_cast<float4*>(&b[4]) = *reinterpret_cast<const float4*>(&wsh[k][tx * 8 + 4]);
#pragma unroll
            for (int i = 0; i < 8; ++i)
#pragma unroll
                for (int j = 0; j < 8; ++j)
                    acc[i][j] = fmaf(a[i], b[j], acc[i][j]);
        }
    }

    float sred[8][NEXP];
#pragma unroll
    for (int i = 0; i < 8; ++i) {
        float hv[8];
#pragma unroll
        for (int j = 0; j < 8; ++j)
            hv[j] = fmaxf(acc[i][j] + b1s[tx * 8 + j], 0.f);
#pragma unroll
        for (int n = 0; n < NEXP; ++n) {
            float ssum = 0.f;
#pragma unroll
            for (int j = 0; j < 8; ++j)
                ssum = fmaf(hv[j], w2s[(tx * 8 + j) * NEXP + n], ssum);
            sred[i][n] = ssum;
        }
    }
#pragma unroll
    for (int i = 0; i < 8; ++i)
#pragma unroll
        for (int n = 0; n < NEXP; ++n) {
            float v = sred[i][n];
            v += __shfl_xor(v, 1);
            v += __shfl_xor(v, 2);
            v += __shfl_xor(v, 4);
            v += __shfl_xor(v, 8);
            sred[i][n] = v;
        }

    if (tx == 0) {
        float* slice = dst + (size_t)htile * T_TOK * NEXP;
#pragma unroll
        for (int i = 0; i < 8; ++i)
#pragma unroll
            for (int n = 0; n < NEXP; ++n)
                slice[(size_t)(m0 + ty * 8 + i) * NEXP + n] = sred[i][n];
    }
}

__global__ __launch_bounds__(256) void finish_simple_kernel(
    const float* __restrict__ part, const float* __restrict__ b2,
    float* __restrict__ out, int nparts)
{
    int t = blockIdx.x * 256 + threadIdx.x;
    if (t >= T_TOK) return;
    float s[NEXP];
#pragma unroll
    for (int n = 0; n < NEXP; ++n) s[n] = 0.f;
    for (int p = 0; p < nparts; ++p) {
        const float* ps = part + (size_t)p * T_TOK * NEXP + (size_t)t * NEXP;
        float4 v0 = *reinterpret_cast<const float4*>(ps);
        float4 v1 = *reinterpret_cast<const float4*>(ps + 4);
        s[0] += v0.x; s[1] += v0.y; s[2] += v0.z; s[3] += v0.w;
        s[4] += v1.x; s[5] += v1.y; s[6] += v1.z; s[7] += v1.w;
    }
#pragma unroll
    for (int n = 0; n < NEXP; ++n) s[n] += b2[n];
    int i1 = 0; float v1 = s[0];
#pragma unroll
    for (int n = 1; n < NEXP; ++n) { if (s[n] > v1) { v1 = s[n]; i1 = n; } }
    int i2 = -1; float v2 = -3.402823466e38f;
#pragma unroll
    for (int n = 0; n < NEXP; ++n) { if (n != i1 && s[n] > v2) { v2 = s[n]; i2 = n; } }
    float e2 = expf(v2 - v1);
    float denom = 1.f + e2;
    float p1 = 1.f / denom;
    float p2 = e2 / denom;
#pragma unroll
    for (int n = 0; n < NEXP; ++n)
        out[(size_t)t * NEXP + n] = (n == i1) ? p1 : ((n == i2) ? p2 : 0.f);
    out[(size_t)T_TOK * NEXP + (size_t)t * 2 + 0] = (float)i1;
    out[(size_t)T_TOK * NEXP + (size_t)t * 2 + 1] = (float)i2;
}

extern "C" void kernel_launch(void* const* d_in, const int* in_sizes, int n_in,
                              void* d_out, int out_size, void* d_ws, size_t ws_size,
                              hipStream_t stream)
{
    const float* x  = (const float*)d_in[0];
    const float* w1 = (const float*)d_in[1];
    const float* b1 = (const float*)d_in[2];
    const float* w2 = (const float*)d_in[3];
    const float* b2 = (const float*)d_in[4];
    float* out = (float*)d_out;

    char* ws = (char*)d_ws;
    _Float16* xhi = (_Float16*)ws;                      // 64 MB @ 0
    _Float16* whi = (_Float16*)(ws + 67108864);         //  8 MB @ 64M
    float* part   = (float*)(ws + 75497472);            // 32 MB @ 72M
    int* counter  = (int*)(ws + 109051904);             //  4 B (+pad)
    int* list     = (int*)(ws + 109052928);             // 128 KB
    float* xg     = (float*)(ws + 109184000);           // 32 MB
    float* rpart  = (float*)(ws + 142738432);           //  8 MB
    const size_t NEED = 151127040;

    if (ws_size >= NEED) {
        split_x_kernel<<<2048, 256, 0, stream>>>(x, xhi, (T_TOK * EDIM) / 4);
        dim3 tg(64, 16);
        split_w1t_kernel<<<tg, 256, 0, stream>>>(w1, whi);
        mfma_score_kernel<<<8192, 256, 0, stream>>>(xhi, whi, b1, w2, part);
        zero_counter_kernel<<<1, 64, 0, stream>>>(counter);
        router_finish_kernel<<<T_TOK / 256, 256, 0, stream>>>(part, b2, out, 32,
                                                              counter, list);
        gather_x_kernel<<<256, 256, 0, stream>>>(x, counter, list, xg);
        dim3 rg(32, MAXR / 64);
        refine_gemm_kernel<<<rg, 256, 0, stream>>>(xg, w1, b1, w2, counter, rpart);
        refine_final_kernel<<<MAXR / 256, 256, 0, stream>>>(counter, list, rpart,
                                                            b2, out);
    } else {
        float* p1 = (float*)d_ws;  // needs 32 MB
        dim3 grid(NHT, T_TOK / BM);
        score_gemm_kernel<<<grid, 256, 0, stream>>>(x, w1, b1, w2, p1);
        finish_simple_kernel<<<T_TOK / 256, 256, 0, stream>>>(p1, b2, out, NHT);
    }
}